// Round 1
// baseline (658.353 us; speedup 1.0000x reference)
//
#include <hip/hip_runtime.h>

// Point2DirSum: directional (hor/ver/diag/adiag) length-5 box sums with zero
// padding. in: (N,C,H,W) fp32, out: (N,4C,H,W) fp32, channel-concat order
// [hor, ver, diag, adiag].
//
// Memory-bound: 134 MB read + 537 MB write. Strategy: LDS-tiled stencil,
// 64x128 tile + halo(2) => 68x132 floats = 35.9 KB LDS (4 blocks/CU).
// Each thread computes 4 consecutive outputs for all 4 directions from a
// 5x8 register patch (aligned float4 LDS reads), float4 global stores.

constexpr int N = 128, C = 16, H = 128, W = 128;
constexpr int TH = 64, TW = 128;
constexpr int HALO = 2;
constexpr int LH = TH + 2 * HALO;   // 68
constexpr int LW = TW + 2 * HALO;   // 132 (mod 4 == 0 -> float4-aligned rows)

__global__ __launch_bounds__(256)
void Point2DirSum_kernel(const float* __restrict__ in, float* __restrict__ out) {
    __shared__ float tile[LH * LW];
    const int tid = threadIdx.x;
    constexpr int TILES_PER_IMG = H / TH;            // 2
    const int img = blockIdx.x / TILES_PER_IMG;      // n*C + c
    const int t   = blockIdx.x % TILES_PER_IMG;
    const int h0  = t * TH;
    const float* __restrict__ inp = in + (size_t)img * H * W;

    // Cooperative load, zero-filled halo (zero padding semantics).
    for (int idx = tid; idx < LH * LW; idx += 256) {
        const int r  = idx / LW;
        const int cc = idx - r * LW;
        const int h  = h0 + r - HALO;
        const int w  = cc - HALO;
        float v = 0.0f;
        if ((unsigned)h < (unsigned)H && (unsigned)w < (unsigned)W)
            v = inp[h * W + w];
        tile[idx] = v;
    }
    __syncthreads();

    const int n = img / C;
    const int c = img - n * C;
    float* __restrict__ outp = out + (((size_t)n * 4 * C + c) * (size_t)H) * W;
    const size_t plane = (size_t)C * H * W;          // stride between dir blocks

    // tile[r][cc] == xp_padded[h0 + r][cc]  (xp = zero-padded input, pad=2)
    // output (h= h0+rl, w= w4+j):
    //   hor  = sum_d tile[rl+2][w4+j+d]
    //   ver  = sum_d tile[rl+d][w4+j+2]
    //   diag = sum_d tile[rl+d][w4+j+d]
    //   adiag= sum_d tile[rl+d][w4+j+4-d]
    constexpr int GROUPS = TH * TW / 4;              // 2048 float4-groups
    for (int g = tid; g < GROUPS; g += 256) {
        const int rl = g >> 5;                       // 32 groups per row
        const int w4 = (g & 31) * 4;

        // 5x8 patch covering all four directions for outputs j=0..3
        float p[5][8];
        #pragma unroll
        for (int d = 0; d < 5; ++d) {
            const float4 a = *(const float4*)&tile[(rl + d) * LW + w4];
            const float4 b = *(const float4*)&tile[(rl + d) * LW + w4 + 4];
            p[d][0] = a.x; p[d][1] = a.y; p[d][2] = a.z; p[d][3] = a.w;
            p[d][4] = b.x; p[d][5] = b.y; p[d][6] = b.z; p[d][7] = b.w;
        }

        float ho[4], ve[4], di[4], ad[4];
        #pragma unroll
        for (int j = 0; j < 4; ++j) {
            float sh = 0.f, sv = 0.f, sd = 0.f, sa = 0.f;
            #pragma unroll
            for (int d = 0; d < 5; ++d) {
                sh += p[2][j + d];
                sv += p[d][j + 2];
                sd += p[d][j + d];
                sa += p[d][j + 4 - d];
            }
            ho[j] = sh; ve[j] = sv; di[j] = sd; ad[j] = sa;
        }

        const int h = h0 + rl;
        const size_t o = (size_t)h * W + w4;
        *(float4*)&outp[o]             = make_float4(ho[0], ho[1], ho[2], ho[3]);
        *(float4*)&outp[o + plane]     = make_float4(ve[0], ve[1], ve[2], ve[3]);
        *(float4*)&outp[o + 2 * plane] = make_float4(di[0], di[1], di[2], di[3]);
        *(float4*)&outp[o + 3 * plane] = make_float4(ad[0], ad[1], ad[2], ad[3]);
    }
}

extern "C" void kernel_launch(void* const* d_in, const int* in_sizes, int n_in,
                              void* d_out, int out_size, void* d_ws, size_t ws_size,
                              hipStream_t stream) {
    const float* in = (const float*)d_in[0];
    float* out = (float*)d_out;
    const int grid = N * C * (H / TH);               // 4096 blocks
    Point2DirSum_kernel<<<grid, 256, 0, stream>>>(in, out);
}